// Round 1
// baseline (2998.822 us; speedup 1.0000x reference)
//
#include <hip/hip_runtime.h>

#define HH 256
#define WW 512
#define HP 260            // H padded by 2 zero rows each side
#define BQ 2
#define NCHX 18           // stored xin channels
#define CHS (HP*WW)       // 133120 per-channel plane
#define HWQ (HH*WW)       // 131072

#define RGASC 287.0f
#define CPC   1004.0f

// ---------------- static device scratch (no ws_size assumptions) -------------
static __device__ float g_xin[BQ*NCHX*CHS];    // (B,18,260,512)
static __device__ float g_PW[25*18*16];        // packed conv weights [t][i][o]
static __device__ float g_W2[25*6*8];          // packed k_vs2 [t][r][j]
static __device__ float g_FC[256*16];          // per-row f_cor contribution [r][o]
static __device__ float g_mean[8];
static __device__ float g_uvs[BQ*3*HWQ*2];     // stage state
static __device__ float g_Ts [BQ*3*HWQ];
static __device__ float g_qs [BQ*3*HWQ];
static __device__ float g_auv[BQ*3*HWQ*2];     // RK4 accumulators
static __device__ float g_aT [BQ*3*HWQ];
static __device__ float g_aq [BQ*3*HWQ];

// map my 12 stored channels -> full 19-channel index
// ch 0..2: T_anom_k (6k+0), 3..5: KE_k (6k+1), 6..8: T_k (6k+4), 9..11: q_k (6k+5)
__device__ __forceinline__ int fullS(int ch) {
  int k = ch % 3, g = ch / 3;
  int o = (g==0) ? 0 : (g==1) ? 1 : (g==2) ? 4 : 5;
  return 6*k + o;
}

// ---------------- weight packing (runs once per launch) ----------------------
__global__ __launch_bounds__(256) void pack_kernel(
    const float* __restrict__ k_ss, const float* __restrict__ k_vs,
    const float* __restrict__ k_sv, const float* __restrict__ k_vv,
    const float* __restrict__ k_vs2, const float* __restrict__ pw_ss,
    const float* __restrict__ f_cor)
{
  int tid = blockIdx.x*256 + threadIdx.x;
  if (tid < 7200) {                       // g_PW[(t*18+i)*16+o]
    int o = tid & 15;
    int i = (tid >> 4) % 18;
    int t = tid / 288;
    int dy = t/5, dx = t%5;
    float val = 0.f;
    if (o < 15) {
      if (o < 9) {                        // scalar outputs: o = typ*3+k -> wait: o%3=k,o/3=typ
        int k = o % 3, typ = o / 3;       // typ 0:DIV 1:TK 2:QK
        int fo = 6*k + 3 + typ;
        if (i < 12) val = k_ss[((fo*19 + fullS(i))*5 + dy)*5 + dx];
        else        val = k_vs[((fo*6 + (i-12))*5 + dy)*5 + dx];
      } else {                            // vector outputs vo = 2k+c
        int vo = o - 9;
        if (i < 12) val = k_sv[((vo*19 + fullS(i))*5 + dy)*5 + dx];
        else        val = k_vv[((vo*6 + (i-12))*5 + dy)*5 + dx];
      }
    }
    g_PW[tid] = val;
  } else if (tid < 8400) {                // g_W2[(t*6+r)*8+j]
    int e = tid - 7200;
    int j = e & 7;
    int r = (e >> 3) % 6;
    int t = e / 48;
    int dy=t/5, dx=t%5;
    float val = 0.f;
    if (j < 6) {
      int k = r % 3;
      int fo = 6*k + ((r<3) ? 4 : 5);     // TK or QK group
      val = k_vs2[((fo*6 + j)*5 + dy)*5 + dx];
    }
    g_W2[e] = val;
  } else if (tid < 8400 + 4096) {         // g_FC[r*16+o]: f_cor channel folded
    int e = tid - 8400;
    int o = e & 15;
    int r = e >> 4;
    float val = 0.f;
    if (o < 15) {
      for (int t=0;t<25;++t) {
        int dy=t/5, dx=t%5;
        int ar = r + dy - 2;
        if (ar < 0 || ar >= HH) continue;
        float f = f_cor[ar];
        float wv;
        if (o < 9) { int k=o%3, typ=o/3; int fo=6*k+3+typ;
                     wv = k_ss[((fo*19+18)*5+dy)*5+dx]; }
        else       { int vo=o-9;
                     wv = k_sv[((vo*19+18)*5+dy)*5+dx]; }
        val += wv * f;
      }
      if (o < 9) { int k=o%3, typ=o/3; int fo=6*k+3+typ;
                   val += pw_ss[fo*19 + 18] * f_cor[r]; }   // pointwise pw_ss f_cor term
    }
    g_FC[e] = val;
  }
}

// ---------------- per-(b,level) mean of stage T ------------------------------
__global__ __launch_bounds__(1024) void mean_kernel(const float* __restrict__ Ta, int useg)
{
  const float* Tp = useg ? g_Ts : Ta;
  int bk = blockIdx.x;                    // 0..5
  const float* p = Tp + (size_t)bk*HWQ;
  double s = 0.0;
  for (int i = threadIdx.x; i < HWQ; i += 1024) s += (double)p[i];
  __shared__ double sh[1024];
  sh[threadIdx.x] = s; __syncthreads();
  for (int off = 512; off > 0; off >>= 1) {
    if (threadIdx.x < off) sh[threadIdx.x] += sh[threadIdx.x + off];
    __syncthreads();
  }
  if (threadIdx.x == 0) g_mean[bk] = (float)(sh[0] / (double)HWQ);
}

// ---------------- build 18-channel padded input field ------------------------
__global__ __launch_bounds__(256) void prep_kernel(
    const float* __restrict__ uva, const float* __restrict__ Ta,
    const float* __restrict__ qa,  const float* __restrict__ ke_w, int useg)
{
  int idx = blockIdx.x*256 + threadIdx.x;
  if (idx >= BQ*HP*WW) return;
  int w  = idx & (WW-1);
  int pr = (idx >> 9) % HP;
  int b  = idx / (WW*HP);
  const float* uvp = useg ? g_uvs : uva;
  const float* Tp  = useg ? g_Ts  : Ta;
  const float* qp  = useg ? g_qs  : qa;

  float outv[18];
  if (pr < 2 || pr >= HP-2) {
    #pragma unroll
    for (int ch=0; ch<18; ++ch) outv[ch] = 0.f;
  } else {
    int r = pr - 2;
    float Tv[3], qv[3], u2[3], uvv[6];
    #pragma unroll
    for (int k=0;k<3;++k) {
      int pix = ((b*3+k)*HH + r)*WW + w;
      Tv[k] = Tp[pix]; qv[k] = qp[pix];
      float u = uvp[pix*2+0], v = uvp[pix*2+1];
      uvv[2*k]=u; uvv[2*k+1]=v;
      u2[k] = u*u + v*v;
    }
    #pragma unroll
    for (int k=0;k<3;++k) outv[k] = Tv[k] - g_mean[b*3+k];
    #pragma unroll
    for (int o=0;o<3;++o)
      outv[3+o] = ke_w[o*3+0]*u2[0] + ke_w[o*3+1]*u2[1] + ke_w[o*3+2]*u2[2];
    #pragma unroll
    for (int k=0;k<3;++k) { outv[6+k]=Tv[k]; outv[9+k]=qv[k]; }
    #pragma unroll
    for (int j=0;j<6;++j) outv[12+j]=uvv[j];
  }
  int base = b*NCHX*CHS + pr*WW + w;
  #pragma unroll
  for (int ch=0; ch<18; ++ch) g_xin[base + ch*CHS] = outv[ch];
}

// ---------------- fused conv + thermodynamics + RK4 --------------------------
__global__ __launch_bounds__(256) void conv_kernel(
    const float* __restrict__ pw_ss, const float* __restrict__ svp,
    const float* __restrict__ f_cor, const float* __restrict__ p_lev,
    const float* __restrict__ delta_p,
    const float* __restrict__ uv0, const float* __restrict__ T0,
    const float* __restrict__ q0,
    float* __restrict__ out, const int* __restrict__ dtp, int stage)
{
  const int tx = threadIdx.x;                 // 64 along W
  const int ty = threadIdx.y;                 // 4 row-groups
  const int b  = blockIdx.z;
  const int c  = (blockIdx.x << 6) + tx;
  const int r0 = (blockIdx.y << 4) + (ty << 2);

  float acc[15][4];
  #pragma unroll
  for (int o=0;o<15;++o)
    #pragma unroll
    for (int px=0;px<4;++px)
      acc[o][px] = g_FC[(r0+px)*16 + o];

  const float* xbase = g_xin + b*NCHX*CHS;

  #pragma unroll 1
  for (int t=0;t<25;++t) {
    const int dy = t/5, dx = t%5;
    const int co = (c + dx - 2) & (WW-1);
    const float* xp = xbase + (r0+dy)*WW + co;
    const float* wp = g_PW + t*288;
    const float* w2 = g_W2 + t*48;
    float sel[6][4], vv[6][4];
    #pragma unroll
    for (int i=0;i<18;++i) {
      const float* xi = xp + i*CHS;
      float v0 = xi[0], v1 = xi[WW], v2 = xi[2*WW], v3 = xi[3*WW];
      if (i>=6 && i<12) { sel[i-6][0]=v0; sel[i-6][1]=v1; sel[i-6][2]=v2; sel[i-6][3]=v3; }
      if (i>=12)        { vv[i-12][0]=v0; vv[i-12][1]=v1; vv[i-12][2]=v2; vv[i-12][3]=v3; }
      #pragma unroll
      for (int o=0;o<15;++o) {
        const float wv = wp[i*16+o];          // wave-uniform -> s_load
        acc[o][0] = fmaf(wv, v0, acc[o][0]);
        acc[o][1] = fmaf(wv, v1, acc[o][1]);
        acc[o][2] = fmaf(wv, v2, acc[o][2]);
        acc[o][3] = fmaf(wv, v3, acc[o][3]);
      }
    }
    // grouped k_vs2: outputs TK_k (r=0..2, sel=T_k) / QK_k (r=3..5, sel=q_k)
    #pragma unroll
    for (int r=0;r<6;++r) {
      float s0=0.f,s1=0.f,s2=0.f,s3=0.f;
      #pragma unroll
      for (int j=0;j<6;++j) {
        const float wv = w2[r*8+j];
        s0 = fmaf(wv, vv[j][0], s0);
        s1 = fmaf(wv, vv[j][1], s1);
        s2 = fmaf(wv, vv[j][2], s2);
        s3 = fmaf(wv, vv[j][3], s3);
      }
      acc[3+r][0] = fmaf(sel[r][0], s0, acc[3+r][0]);
      acc[3+r][1] = fmaf(sel[r][1], s1, acc[3+r][1]);
      acc[3+r][2] = fmaf(sel[r][2], s2, acc[3+r][2]);
      acc[3+r][3] = fmaf(sel[r][3], s3, acc[3+r][3]);
    }
  }

  // ----------------- epilogue: pointwise physics + RK4 -----------------------
  const float dtf = (float)(*dtp);
  const float an  = (stage==2) ? dtf : 0.5f*dtf;
  const float wa  = 2.0f;
  const float c6  = dtf/6.0f;
  const float p0=p_lev[0], p1=p_lev[1], p2=p_lev[2];
  const float dp0=delta_p[0], dp1=delta_p[1], dp2=delta_p[2];
  const float r10 = 1.0f/(p1-p0), r20 = 1.0f/(p2-p0), r21 = 1.0f/(p2-p1);
  const float roc = RGASC/CPC;
  const float rp0 = 1.0f/p0, rp1 = 1.0f/p1, rp2 = 1.0f/p2;
  const int OUT_T = BQ*3*HWQ*2;
  const int OUT_Q = OUT_T + BQ*3*HWQ;

  for (int px=0;px<4;++px) {
    const int r = r0 + px;
    const float* xc = xbase + (r+2)*WW + c;   // center (padded row r+2)
    float xs[12];
    #pragma unroll
    for (int ch=0;ch<12;++ch) xs[ch] = xc[ch*CHS];
    float uc[6];
    #pragma unroll
    for (int j=0;j<6;++j) uc[j] = xc[(12+j)*CHS];
    const float fcv = f_cor[r];

    // pw_ss pointwise for the 9 scalar outputs (f_cor part already in g_FC)
    float ps[9];
    #pragma unroll
    for (int o=0;o<9;++o) {
      const int fo = 6*(o%3) + 3 + o/3;
      float s = 0.f;
      #pragma unroll
      for (int ch=0;ch<12;++ch) s = fmaf(pw_ss[fo*19 + fullS(ch)], xs[ch], s);
      ps[o] = s;
    }
    // svp projections a0,a1 over nonzero x_s channels + f_cor
    float a0[3]={0,0,0}, a1[3]={0,0,0};
    #pragma unroll
    for (int ch=0;ch<12;++ch) {
      const int fi = fullS(ch);
      #pragma unroll
      for (int v=0;v<3;++v) {
        a0[v] = fmaf(svp[(fi*3+v)*2+0], xs[ch], a0[v]);
        a1[v] = fmaf(svp[(fi*3+v)*2+1], xs[ch], a1[v]);
      }
    }
    #pragma unroll
    for (int v=0;v<3;++v) {
      a0[v] = fmaf(svp[(18*3+v)*2+0], fcv, a0[v]);
      a1[v] = fmaf(svp[(18*3+v)*2+1], fcv, a1[v]);
    }

    float kuv[6], kT[3], kq[3], dv[3];
    #pragma unroll
    for (int k=0;k<3;++k) {
      const float u = uc[2*k], v = uc[2*k+1];
      float y0 = acc[9+2*k  ][px];
      float y1 = acc[9+2*k+1][px];
      y0 += a0[k]*u + a1[k]*(-v);
      y1 += a0[k]*v + a1[k]*( u);
      kuv[2*k]=y0; kuv[2*k+1]=y1;
    }
    #pragma unroll
    for (int k=0;k<3;++k) {
      dv[k] = acc[k][px]   + ps[k];
      kT[k] = acc[3+k][px] + ps[3+k];
      kq[k] = acc[6+k][px] + ps[6+k];
    }
    const float oh1 = dv[0]*dp0;
    const float oh2 = oh1 + dv[1]*dp1;
    const float oh3 = oh2 + dv[2]*dp2;
    const float om0 = 0.5f*oh1, om1 = 0.5f*(oh1+oh2), om2 = 0.5f*(oh2+oh3);
    const float Tc0 = xs[6], Tc1 = xs[7], Tc2 = xs[8];
    kT[0] += om0*(roc*Tc0*rp0 - (Tc1-Tc0)*r10);
    kT[1] += om1*(roc*Tc1*rp1 - (Tc2-Tc0)*r20);
    kT[2] += om2*(roc*Tc2*rp2 - (Tc2-Tc1)*r21);

    #pragma unroll
    for (int k=0;k<3;++k) {
      const int pT = ((b*3+k)*HH + r)*WW + c;
      const int pU = pT*2;
      if (stage == 0) {
        g_aT[pT] = kT[k];  g_aq[pT] = kq[k];
        g_auv[pU] = kuv[2*k];  g_auv[pU+1] = kuv[2*k+1];
        g_Ts[pT] = T0[pT] + an*kT[k];
        g_qs[pT] = q0[pT] + an*kq[k];
        g_uvs[pU]   = uv0[pU]   + an*kuv[2*k];
        g_uvs[pU+1] = uv0[pU+1] + an*kuv[2*k+1];
      } else if (stage < 3) {
        g_aT[pT] += wa*kT[k];  g_aq[pT] += wa*kq[k];
        g_auv[pU] += wa*kuv[2*k];  g_auv[pU+1] += wa*kuv[2*k+1];
        g_Ts[pT] = T0[pT] + an*kT[k];
        g_qs[pT] = q0[pT] + an*kq[k];
        g_uvs[pU]   = uv0[pU]   + an*kuv[2*k];
        g_uvs[pU+1] = uv0[pU+1] + an*kuv[2*k+1];
      } else {
        out[pU]         = uv0[pU]   + c6*(g_auv[pU]   + kuv[2*k]);
        out[pU+1]       = uv0[pU+1] + c6*(g_auv[pU+1] + kuv[2*k+1]);
        out[OUT_T + pT] = T0[pT]    + c6*(g_aT[pT] + kT[k]);
        out[OUT_Q + pT] = q0[pT]    + c6*(g_aq[pT] + kq[k]);
      }
    }
  }
}

// -----------------------------------------------------------------------------
extern "C" void kernel_launch(void* const* d_in, const int* in_sizes, int n_in,
                              void* d_out, int out_size, void* d_ws, size_t ws_size,
                              hipStream_t stream) {
  (void)in_sizes; (void)n_in; (void)d_ws; (void)ws_size; (void)out_size;
  const float* uv0   = (const float*)d_in[0];
  const float* T0    = (const float*)d_in[1];
  const float* q0    = (const float*)d_in[2];
  const float* k_ss  = (const float*)d_in[3];
  const float* k_vs  = (const float*)d_in[4];
  const float* k_sv  = (const float*)d_in[5];
  const float* k_vv  = (const float*)d_in[6];
  const float* k_vs2 = (const float*)d_in[7];
  const float* pw_ss = (const float*)d_in[8];
  const float* svp   = (const float*)d_in[9];
  const float* ke_w  = (const float*)d_in[10];
  const float* f_cor = (const float*)d_in[11];
  const float* p_lev = (const float*)d_in[12];
  const float* dpv   = (const float*)d_in[13];
  const int*   dtp   = (const int*)d_in[14];
  float* out = (float*)d_out;

  pack_kernel<<<49, 256, 0, stream>>>(k_ss, k_vs, k_sv, k_vv, k_vs2, pw_ss, f_cor);

  for (int st = 0; st < 4; ++st) {
    mean_kernel<<<6, 1024, 0, stream>>>(T0, st > 0);
    prep_kernel<<<1040, 256, 0, stream>>>(uv0, T0, q0, ke_w, st > 0);
    conv_kernel<<<dim3(8,16,2), dim3(64,4,1), 0, stream>>>(
        pw_ss, svp, f_cor, p_lev, dpv, uv0, T0, q0, out, dtp, st);
  }
}

// Round 2
// 777.651 us; speedup vs baseline: 3.8563x; 3.8563x over previous
//
#include <hip/hip_runtime.h>

#define HH 256
#define WW 512
#define HP 260            // H padded by 2 zero rows each side
#define BQ 2
#define NCHX 18           // stored xin channels
#define CHS (HP*WW)       // 133120 per-channel plane
#define HWQ (HH*WW)       // 131072

#define RGASC 287.0f
#define CPC   1004.0f

// ---------------- static device scratch (no ws_size assumptions) -------------
static __device__ float g_xin[BQ*NCHX*CHS];    // (B,18,260,512)
static __device__ float g_PW[25*18*16];        // packed conv weights [t][i][o]
static __device__ float g_W2[25*6*8];          // packed k_vs2 [t][r][j]
static __device__ float g_FC[256*16];          // per-row f_cor contribution [r][o]
static __device__ float g_mean[8];
static __device__ float g_uvs[BQ*3*HWQ*2];     // stage state
static __device__ float g_Ts [BQ*3*HWQ];
static __device__ float g_qs [BQ*3*HWQ];
static __device__ float g_auv[BQ*3*HWQ*2];     // RK4 accumulators
static __device__ float g_aT [BQ*3*HWQ];
static __device__ float g_aq [BQ*3*HWQ];

// map my 12 stored channels -> full 19-channel index
// ch 0..2: T_anom_k (6k+0), 3..5: KE_k (6k+1), 6..8: T_k (6k+4), 9..11: q_k (6k+5)
__device__ __forceinline__ int fullS(int ch) {
  int k = ch % 3, g = ch / 3;
  int o = (g==0) ? 0 : (g==1) ? 1 : (g==2) ? 4 : 5;
  return 6*k + o;
}

// ---------------- weight packing (runs once per launch) ----------------------
__global__ __launch_bounds__(256) void pack_kernel(
    const float* __restrict__ k_ss, const float* __restrict__ k_vs,
    const float* __restrict__ k_sv, const float* __restrict__ k_vv,
    const float* __restrict__ k_vs2, const float* __restrict__ pw_ss,
    const float* __restrict__ f_cor)
{
  int tid = blockIdx.x*256 + threadIdx.x;
  if (tid < 7200) {                       // g_PW[(t*18+i)*16+o]
    int o = tid & 15;
    int i = (tid >> 4) % 18;
    int t = tid / 288;
    int dy = t/5, dx = t%5;
    float val = 0.f;
    if (o < 15) {
      if (o < 9) {                        // scalar outputs: o%3=k, o/3=typ (0:DIV 1:TK 2:QK)
        int k = o % 3, typ = o / 3;
        int fo = 6*k + 3 + typ;
        if (i < 12) val = k_ss[((fo*19 + fullS(i))*5 + dy)*5 + dx];
        else        val = k_vs[((fo*6 + (i-12))*5 + dy)*5 + dx];
      } else {                            // vector outputs vo = 2k+c
        int vo = o - 9;
        if (i < 12) val = k_sv[((vo*19 + fullS(i))*5 + dy)*5 + dx];
        else        val = k_vv[((vo*6 + (i-12))*5 + dy)*5 + dx];
      }
    }
    g_PW[tid] = val;
  } else if (tid < 8400) {                // g_W2[(t*6+r)*8+j]
    int e = tid - 7200;
    int j = e & 7;
    int r = (e >> 3) % 6;
    int t = e / 48;
    int dy=t/5, dx=t%5;
    float val = 0.f;
    if (j < 6) {
      int k = r % 3;
      int fo = 6*k + ((r<3) ? 4 : 5);     // TK or QK group
      val = k_vs2[((fo*6 + j)*5 + dy)*5 + dx];
    }
    g_W2[e] = val;
  } else if (tid < 8400 + 4096) {         // g_FC[r*16+o]: f_cor channel folded
    int e = tid - 8400;
    int o = e & 15;
    int r = e >> 4;
    float val = 0.f;
    if (o < 15) {
      for (int t=0;t<25;++t) {
        int dy=t/5, dx=t%5;
        int ar = r + dy - 2;
        if (ar < 0 || ar >= HH) continue;
        float f = f_cor[ar];
        float wv;
        if (o < 9) { int k=o%3, typ=o/3; int fo=6*k+3+typ;
                     wv = k_ss[((fo*19+18)*5+dy)*5+dx]; }
        else       { int vo=o-9;
                     wv = k_sv[((vo*19+18)*5+dy)*5+dx]; }
        val += wv * f;
      }
      if (o < 9) { int k=o%3, typ=o/3; int fo=6*k+3+typ;
                   val += pw_ss[fo*19 + 18] * f_cor[r]; }   // pointwise pw_ss f_cor term
    }
    g_FC[e] = val;
  }
}

// ---------------- per-(b,level) mean of stage T ------------------------------
__global__ __launch_bounds__(1024) void mean_kernel(const float* __restrict__ Ta, int useg)
{
  const float* Tp = useg ? g_Ts : Ta;
  int bk = blockIdx.x;                    // 0..5
  const float* p = Tp + (size_t)bk*HWQ;
  double s = 0.0;
  for (int i = threadIdx.x; i < HWQ; i += 1024) s += (double)p[i];
  __shared__ double sh[1024];
  sh[threadIdx.x] = s; __syncthreads();
  for (int off = 512; off > 0; off >>= 1) {
    if (threadIdx.x < off) sh[threadIdx.x] += sh[threadIdx.x + off];
    __syncthreads();
  }
  if (threadIdx.x == 0) g_mean[bk] = (float)(sh[0] / (double)HWQ);
}

// ---------------- build 18-channel padded input field ------------------------
__global__ __launch_bounds__(256) void prep_kernel(
    const float* __restrict__ uva, const float* __restrict__ Ta,
    const float* __restrict__ qa,  const float* __restrict__ ke_w, int useg)
{
  int idx = blockIdx.x*256 + threadIdx.x;
  if (idx >= BQ*HP*WW) return;
  int w  = idx & (WW-1);
  int pr = (idx >> 9) % HP;
  int b  = idx / (WW*HP);
  const float* uvp = useg ? g_uvs : uva;
  const float* Tp  = useg ? g_Ts  : Ta;
  const float* qp  = useg ? g_qs  : qa;

  float outv[18];
  if (pr < 2 || pr >= HP-2) {
    #pragma unroll
    for (int ch=0; ch<18; ++ch) outv[ch] = 0.f;
  } else {
    int r = pr - 2;
    float Tv[3], qv[3], u2[3], uvv[6];
    #pragma unroll
    for (int k=0;k<3;++k) {
      int pix = ((b*3+k)*HH + r)*WW + w;
      Tv[k] = Tp[pix]; qv[k] = qp[pix];
      float u = uvp[pix*2+0], v = uvp[pix*2+1];
      uvv[2*k]=u; uvv[2*k+1]=v;
      u2[k] = u*u + v*v;
    }
    #pragma unroll
    for (int k=0;k<3;++k) outv[k] = Tv[k] - g_mean[b*3+k];
    #pragma unroll
    for (int o=0;o<3;++o)
      outv[3+o] = ke_w[o*3+0]*u2[0] + ke_w[o*3+1]*u2[1] + ke_w[o*3+2]*u2[2];
    #pragma unroll
    for (int k=0;k<3;++k) { outv[6+k]=Tv[k]; outv[9+k]=qv[k]; }
    #pragma unroll
    for (int j=0;j<6;++j) outv[12+j]=uvv[j];
  }
  int base = b*NCHX*CHS + pr*WW + w;
  #pragma unroll
  for (int ch=0; ch<18; ++ch) g_xin[base + ch*CHS] = outv[ch];
}

// ---------------- fused conv + thermodynamics + RK4 --------------------------
// 1 pixel/thread (64x4 tile), LDS-staged 18ch x 8row x 68col f32 tile (39168 B).
// acc[15]+sel[6]+vv[6] ~ 50 VGPR: no spills (round-1 failure mode).
__global__ __launch_bounds__(256, 4) void conv_kernel(
    const float* __restrict__ pw_ss, const float* __restrict__ svp,
    const float* __restrict__ f_cor, const float* __restrict__ p_lev,
    const float* __restrict__ delta_p,
    const float* __restrict__ uv0, const float* __restrict__ T0,
    const float* __restrict__ q0,
    float* __restrict__ out, const int* __restrict__ dtp, int stage)
{
  __shared__ float s_x[NCHX][8][68];          // 39168 B

  const int tx = threadIdx.x;                 // 64 along W
  const int ty = threadIdx.y;                 // 4 rows
  const int b  = blockIdx.z;
  const int c0 = (blockIdx.x << 6);
  const int c  = c0 + tx;
  const int R0 = (blockIdx.y << 2);
  const int r  = R0 + ty;                     // output row (wave-uniform)

  // ---- stage tile: lds[ch][lr][lc] = xin[ch][R0+lr][(c0+lc-2)&511] ----------
  {
    const float* xb = g_xin + b*NCHX*CHS;
    float* sp = &s_x[0][0][0];
    for (int e = (ty<<6) + tx; e < NCHX*8*68; e += 256) {
      int ch  = e / (8*68);
      int rem = e - ch*(8*68);
      int lr  = rem / 68;
      int lc  = rem - lr*68;
      int col = (c0 + lc - 2) & (WW-1);
      sp[e] = xb[ch*CHS + (R0+lr)*WW + col];
    }
  }
  __syncthreads();

  float acc[15];
  #pragma unroll
  for (int o=0;o<15;++o) acc[o] = g_FC[r*16 + o];

  #pragma unroll 1
  for (int t=0;t<25;++t) {
    const int dy = t/5, dx = t%5;
    const float* wp = g_PW + t*288;
    const float* w2 = g_W2 + t*48;
    const float* xr = &s_x[0][ty+dy][tx+dx];  // per-channel stride 8*68
    float sel[6], vv[6];
    #pragma unroll
    for (int i=0;i<18;++i) {
      const float v = xr[i*(8*68)];
      if (i>=6 && i<12) sel[i-6] = v;
      if (i>=12)        vv[i-12] = v;
      #pragma unroll
      for (int o=0;o<15;++o)
        acc[o] = fmaf(wp[i*16+o], v, acc[o]); // wave-uniform weight -> s_load
    }
    // grouped k_vs2: outputs TK_k (rr=0..2, sel=T_k) / QK_k (rr=3..5, sel=q_k)
    #pragma unroll
    for (int rr=0;rr<6;++rr) {
      float s = 0.f;
      #pragma unroll
      for (int j=0;j<6;++j) s = fmaf(w2[rr*8+j], vv[j], s);
      acc[3+rr] = fmaf(sel[rr], s, acc[3+rr]);
    }
  }

  // ----------------- epilogue: pointwise physics + RK4 -----------------------
  const float dtf = (float)(*dtp);
  const float an  = (stage==2) ? dtf : 0.5f*dtf;
  const float wa  = 2.0f;
  const float c6  = dtf/6.0f;
  const float p0=p_lev[0], p1=p_lev[1], p2=p_lev[2];
  const float dp0=delta_p[0], dp1=delta_p[1], dp2=delta_p[2];
  const float r10 = 1.0f/(p1-p0), r20 = 1.0f/(p2-p0), r21 = 1.0f/(p2-p1);
  const float roc = RGASC/CPC;
  const float rp0 = 1.0f/p0, rp1 = 1.0f/p1, rp2 = 1.0f/p2;
  const int OUT_T = BQ*3*HWQ*2;
  const int OUT_Q = OUT_T + BQ*3*HWQ;

  float xs[12], uc[6];
  #pragma unroll
  for (int ch=0;ch<12;++ch) xs[ch] = s_x[ch][ty+2][tx+2];
  #pragma unroll
  for (int j=0;j<6;++j)     uc[j]  = s_x[12+j][ty+2][tx+2];
  const float fcv = f_cor[r];

  // pw_ss pointwise for the 9 scalar outputs (f_cor part already in g_FC)
  float ps[9];
  #pragma unroll
  for (int o=0;o<9;++o) {
    const int fo = 6*(o%3) + 3 + o/3;
    float s = 0.f;
    #pragma unroll
    for (int ch=0;ch<12;++ch) s = fmaf(pw_ss[fo*19 + fullS(ch)], xs[ch], s);
    ps[o] = s;
  }
  // svp projections a0,a1 over nonzero x_s channels + f_cor
  float a0[3]={0,0,0}, a1[3]={0,0,0};
  #pragma unroll
  for (int ch=0;ch<12;++ch) {
    const int fi = fullS(ch);
    #pragma unroll
    for (int v=0;v<3;++v) {
      a0[v] = fmaf(svp[(fi*3+v)*2+0], xs[ch], a0[v]);
      a1[v] = fmaf(svp[(fi*3+v)*2+1], xs[ch], a1[v]);
    }
  }
  #pragma unroll
  for (int v=0;v<3;++v) {
    a0[v] = fmaf(svp[(18*3+v)*2+0], fcv, a0[v]);
    a1[v] = fmaf(svp[(18*3+v)*2+1], fcv, a1[v]);
  }

  float kuv[6], kT[3], kq[3], dv[3];
  #pragma unroll
  for (int k=0;k<3;++k) {
    const float u = uc[2*k], v = uc[2*k+1];
    float y0 = acc[9+2*k  ];
    float y1 = acc[9+2*k+1];
    y0 += a0[k]*u + a1[k]*(-v);
    y1 += a0[k]*v + a1[k]*( u);
    kuv[2*k]=y0; kuv[2*k+1]=y1;
  }
  #pragma unroll
  for (int k=0;k<3;++k) {
    dv[k] = acc[k]   + ps[k];
    kT[k] = acc[3+k] + ps[3+k];
    kq[k] = acc[6+k] + ps[6+k];
  }
  const float oh1 = dv[0]*dp0;
  const float oh2 = oh1 + dv[1]*dp1;
  const float oh3 = oh2 + dv[2]*dp2;
  const float om0 = 0.5f*oh1, om1 = 0.5f*(oh1+oh2), om2 = 0.5f*(oh2+oh3);
  const float Tc0 = xs[6], Tc1 = xs[7], Tc2 = xs[8];
  kT[0] += om0*(roc*Tc0*rp0 - (Tc1-Tc0)*r10);
  kT[1] += om1*(roc*Tc1*rp1 - (Tc2-Tc0)*r20);
  kT[2] += om2*(roc*Tc2*rp2 - (Tc2-Tc1)*r21);

  #pragma unroll
  for (int k=0;k<3;++k) {
    const int pT = ((b*3+k)*HH + r)*WW + c;
    const int pU = pT*2;
    if (stage == 0) {
      g_aT[pT] = kT[k];  g_aq[pT] = kq[k];
      g_auv[pU] = kuv[2*k];  g_auv[pU+1] = kuv[2*k+1];
      g_Ts[pT] = T0[pT] + an*kT[k];
      g_qs[pT] = q0[pT] + an*kq[k];
      g_uvs[pU]   = uv0[pU]   + an*kuv[2*k];
      g_uvs[pU+1] = uv0[pU+1] + an*kuv[2*k+1];
    } else if (stage < 3) {
      g_aT[pT] += wa*kT[k];  g_aq[pT] += wa*kq[k];
      g_auv[pU] += wa*kuv[2*k];  g_auv[pU+1] += wa*kuv[2*k+1];
      g_Ts[pT] = T0[pT] + an*kT[k];
      g_qs[pT] = q0[pT] + an*kq[k];
      g_uvs[pU]   = uv0[pU]   + an*kuv[2*k];
      g_uvs[pU+1] = uv0[pU+1] + an*kuv[2*k+1];
    } else {
      out[pU]         = uv0[pU]   + c6*(g_auv[pU]   + kuv[2*k]);
      out[pU+1]       = uv0[pU+1] + c6*(g_auv[pU+1] + kuv[2*k+1]);
      out[OUT_T + pT] = T0[pT]    + c6*(g_aT[pT] + kT[k]);
      out[OUT_Q + pT] = q0[pT]    + c6*(g_aq[pT] + kq[k]);
    }
  }
}

// -----------------------------------------------------------------------------
extern "C" void kernel_launch(void* const* d_in, const int* in_sizes, int n_in,
                              void* d_out, int out_size, void* d_ws, size_t ws_size,
                              hipStream_t stream) {
  (void)in_sizes; (void)n_in; (void)d_ws; (void)ws_size; (void)out_size;
  const float* uv0   = (const float*)d_in[0];
  const float* T0    = (const float*)d_in[1];
  const float* q0    = (const float*)d_in[2];
  const float* k_ss  = (const float*)d_in[3];
  const float* k_vs  = (const float*)d_in[4];
  const float* k_sv  = (const float*)d_in[5];
  const float* k_vv  = (const float*)d_in[6];
  const float* k_vs2 = (const float*)d_in[7];
  const float* pw_ss = (const float*)d_in[8];
  const float* svp   = (const float*)d_in[9];
  const float* ke_w  = (const float*)d_in[10];
  const float* f_cor = (const float*)d_in[11];
  const float* p_lev = (const float*)d_in[12];
  const float* dpv   = (const float*)d_in[13];
  const int*   dtp   = (const int*)d_in[14];
  float* out = (float*)d_out;

  pack_kernel<<<49, 256, 0, stream>>>(k_ss, k_vs, k_sv, k_vv, k_vs2, pw_ss, f_cor);

  for (int st = 0; st < 4; ++st) {
    mean_kernel<<<6, 1024, 0, stream>>>(T0, st > 0);
    prep_kernel<<<1040, 256, 0, stream>>>(uv0, T0, q0, ke_w, st > 0);
    conv_kernel<<<dim3(8,64,2), dim3(64,4,1), 0, stream>>>(
        pw_ss, svp, f_cor, p_lev, dpv, uv0, T0, q0, out, dtp, st);
  }
}

// Round 3
// 229.018 us; speedup vs baseline: 13.0943x; 3.3956x over previous
//
#include <hip/hip_runtime.h>

#define HH 256
#define WW 512
#define HP 260            // H padded by 2 zero rows each side
#define BQ 2
#define HWQ (HH*WW)
#define TW 68             // LDS tile cols (64 + 4 halo)
#define TH 8              // LDS tile rows (4 out + 4 halo)
#define CELLL 20          // LDS cell stride in dwords (80B; global cell is 64B)

#define RGASC 287.0f
#define CPC   1004.0f

typedef float f32x4 __attribute__((ext_vector_type(4)));
typedef short s16x8 __attribute__((ext_vector_type(8)));

// ---------------- static device scratch -------------------------------------
static __device__ uint4 g_xbf[BQ*HP*WW*4];   // bf16 field: cell = 32 bf16 slots (64B)
static __device__ uint4 g_Wm[25*64];         // packed A-fragments [tap][lane]
static __device__ float g_W2[25*6*8];        // grouped (k_vs2) weights [t][rr][j]
static __device__ float g_FC[HH*16];         // f_cor conv row-term [r][o]
static __device__ float g_mean[8];
static __device__ float g_part[6*512];       // per-block partial sums for means
static __device__ float g_uvs[BQ*3*HWQ*2];   // stage state
static __device__ float g_Ts [BQ*3*HWQ];
static __device__ float g_qs [BQ*3*HWQ];
static __device__ float g_auv[BQ*3*HWQ*2];   // RK4 accumulators
static __device__ float g_aT [BQ*3*HWQ];
static __device__ float g_aq [BQ*3*HWQ];

// Slot map (bf16 cell, 32 slots): 0-2 T_anom k, 3-5 KE k, 6,7 zero,
// 8-13 T0,T1,T2,q0,q1,q2, 14,15 zero, 16-21 u0,v0,u1,v1,u2,v2, 22-31 zero.
// Output map o: 0-2 DIV k, 3-5 TK k, 6-8 QK k, 9-14 (U0,V0,U1,V1,U2,V2), 15 pad.

__device__ __forceinline__ unsigned short f2bf(float f) {   // RNE f32->bf16
  unsigned int u = __builtin_bit_cast(unsigned int, f);
  u += 0x7fffu + ((u >> 16) & 1u);
  return (unsigned short)(u >> 16);
}
__device__ __forceinline__ float bflo(unsigned int d) {
  return __builtin_bit_cast(float, d << 16);
}
__device__ __forceinline__ float bfhi(unsigned int d) {
  return __builtin_bit_cast(float, d & 0xffff0000u);
}

// ---------------- weight packing (once per launch) ---------------------------
__global__ __launch_bounds__(256) void pack_kernel(
    const float* __restrict__ k_ss, const float* __restrict__ k_vs,
    const float* __restrict__ k_sv, const float* __restrict__ k_vv,
    const float* __restrict__ k_vs2, const float* __restrict__ f_cor)
{
  int tid = blockIdx.x*256 + threadIdx.x;
  if (tid < 1600) {                       // A-fragments g_Wm[t][lane]
    int l = tid & 63, t = tid >> 6;
    int o = l & 15, g = l >> 4;
    int dy = t/5, dx = t%5;
    unsigned short h[8];
    #pragma unroll
    for (int e=0;e<8;++e) {
      int s = 8*g + e; float val = 0.f;
      if (o < 15) {
        int ch = -1, j = -1;
        if (s < 6)                 ch = 6*(s%3) + (s/3);          // T_anom / KE
        else if (s >= 8 && s < 14) { int ss=s-8; ch = 6*(ss%3) + (ss<3?4:5); } // T / q
        else if (s >= 16 && s < 22) j = s - 16;                    // uv
        if (ch >= 0 || j >= 0) {
          if (o < 9) { int fo = 6*(o%3) + 3 + o/3;                 // DIV/TK/QK
            val = (j>=0) ? k_vs[((fo*6+j)*5+dy)*5+dx] : k_ss[((fo*19+ch)*5+dy)*5+dx];
          } else { int vo = o - 9;
            val = (j>=0) ? k_vv[((vo*6+j)*5+dy)*5+dx] : k_sv[((vo*19+ch)*5+dy)*5+dx];
          }
        }
      }
      h[e] = f2bf(val);
    }
    uint4 wv;
    wv.x = h[0] | ((unsigned)h[1]<<16);  wv.y = h[2] | ((unsigned)h[3]<<16);
    wv.z = h[4] | ((unsigned)h[5]<<16);  wv.w = h[6] | ((unsigned)h[7]<<16);
    g_Wm[tid] = wv;
  } else if (tid < 2800) {                // g_W2[t][rr][8]
    int e = tid - 1600;
    int j = e & 7, rr = (e >> 3) % 6, t = e / 48;
    int dy = t/5, dx = t%5;
    float val = 0.f;
    if (j < 6) {
      int k = rr % 3;
      int fo = 6*k + ((rr < 3) ? 4 : 5);  // TK or QK channel
      val = k_vs2[((fo*6 + j)*5 + dy)*5 + dx];
    }
    g_W2[e] = val;
  } else if (tid < 2800 + HH*16) {        // g_FC[r][o]: f_cor channel conv term
    int e = tid - 2800;
    int o = e & 15, r = e >> 4;
    float val = 0.f;
    if (o < 15) {
      for (int t=0;t<25;++t) {
        int dy = t/5, dx = t%5;
        int ar = r + dy - 2;
        if (ar < 0 || ar >= HH) continue;
        float f = f_cor[ar];
        float wv;
        if (o < 9) { int fo = 6*(o%3) + 3 + o/3; wv = k_ss[((fo*19+18)*5+dy)*5+dx]; }
        else       { int vo = o - 9;             wv = k_sv[((vo*19+18)*5+dy)*5+dx]; }
        val += wv * f;
      }
    }
    g_FC[e] = val;
  }
}

// ---------------- per-(b,level) partial means of input T ---------------------
__global__ __launch_bounds__(256) void meanpart0_kernel(const float* __restrict__ T0)
{
  int bk = blockIdx.y, chunk = blockIdx.x;
  float v = T0[bk*HWQ + chunk*256 + threadIdx.x];
  int l = threadIdx.x & 63, w = threadIdx.x >> 6;
  #pragma unroll
  for (int off=32; off; off >>= 1) v += __shfl_down(v, off);
  __shared__ float sr[4];
  if (l == 0) sr[w] = v;
  __syncthreads();
  if (threadIdx.x == 0) g_part[bk*512 + chunk] = sr[0]+sr[1]+sr[2]+sr[3];
}

__global__ __launch_bounds__(64) void meancomb_kernel()
{
  int bk = blockIdx.x, l = threadIdx.x;
  float s = 0.f;
  #pragma unroll
  for (int i=0;i<8;++i) s += g_part[bk*512 + l + 64*i];
  #pragma unroll
  for (int off=32; off; off >>= 1) s += __shfl_down(s, off);
  if (l == 0) g_mean[bk] = s * (1.0f/(float)HWQ);
}

// ---------------- build bf16 channel-contiguous padded field -----------------
__global__ __launch_bounds__(256) void prep_kernel(
    const float* __restrict__ uva, const float* __restrict__ Ta,
    const float* __restrict__ qa,  const float* __restrict__ ke_w, int useg)
{
  int idx = blockIdx.x*256 + threadIdx.x;       // cell index (b,pr,col)
  if (idx >= BQ*HP*WW) return;
  int w  = idx & (WW-1);
  int pr = (idx >> 9) % HP;
  int b  = idx / (WW*HP);
  const float* uvp = useg ? g_uvs : uva;
  const float* Tp  = useg ? g_Ts  : Ta;
  const float* qp  = useg ? g_qs  : qa;

  unsigned short h[24];
  #pragma unroll
  for (int s=0;s<24;++s) h[s] = 0;
  if (pr >= 2 && pr < HP-2) {
    int r = pr - 2;
    float Tv[3], qv[3], u2[3];
    #pragma unroll
    for (int k=0;k<3;++k) {
      int pix = ((b*3+k)*HH + r)*WW + w;
      Tv[k] = Tp[pix]; qv[k] = qp[pix];
      float u = uvp[2*pix], v = uvp[2*pix+1];
      u2[k] = u*u + v*v;
      h[16+2*k] = f2bf(u); h[17+2*k] = f2bf(v);
    }
    #pragma unroll
    for (int k=0;k<3;++k) {
      h[k]    = f2bf(Tv[k] - g_mean[b*3+k]);
      h[8+k]  = f2bf(Tv[k]);
      h[11+k] = f2bf(qv[k]);
    }
    #pragma unroll
    for (int o=0;o<3;++o)
      h[3+o] = f2bf(ke_w[o*3+0]*u2[0] + ke_w[o*3+1]*u2[1] + ke_w[o*3+2]*u2[2]);
  }
  unsigned int u32[12];
  #pragma unroll
  for (int i=0;i<12;++i) u32[i] = h[2*i] | ((unsigned)h[2*i+1] << 16);
  uint4* dst = g_xbf + (size_t)idx*4;
  dst[0] = make_uint4(u32[0],u32[1],u32[2],u32[3]);
  dst[1] = make_uint4(u32[4],u32[5],u32[6],u32[7]);
  dst[2] = make_uint4(u32[8],u32[9],u32[10],u32[11]);
  dst[3] = make_uint4(0,0,0,0);
}

// ---------------- MFMA conv + grouped + physics + RK4 ------------------------
__global__ __launch_bounds__(256, 2) void conv_kernel(
    const float* __restrict__ f_cor, const float* __restrict__ p_lev,
    const float* __restrict__ delta_p,
    const float* __restrict__ uv0, const float* __restrict__ T0,
    const float* __restrict__ q0,
    float* __restrict__ out, const int* __restrict__ dtp, int stage)
{
  __shared__ unsigned int s_mem[TH*TW*CELLL];   // 43520 B; reused for transpose
  __shared__ float s_red[4][3];

  const int tid = threadIdx.x;
  const int w   = tid >> 6;                     // wave 0..3 -> output row
  const int l   = tid & 63;
  const int b   = blockIdx.z;
  const int c0  = blockIdx.x << 6;
  const int R0  = blockIdx.y << 2;
  const int r   = R0 + w;

  // ---- stage tile: cell(lr,lc) <- g_xbf[b][R0+lr][(c0+lc-2)&511] ------------
  {
    const uint4* src = g_xbf + (size_t)b*HP*WW*4;
    char* sb = (char*)s_mem;
    for (int e = tid; e < TH*TW*4; e += 256) {
      int chunk = e & 3, cell = e >> 2;
      int lr = cell / TW, lc = cell - lr*TW;
      int col = (c0 + lc - 2) & (WW-1);
      uint4 v = src[(size_t)(((R0+lr)*WW + col))*4 + chunk];
      *(uint4*)(sb + cell*80 + chunk*16) = v;
    }
  }
  __syncthreads();

  const int g = l >> 4;
  const int m = l & 15;
  const char* sb = (const char*)s_mem;

  f32x4 acc[4];
  {
    float4 fc = *(const float4*)(g_FC + r*16 + g*4);
    #pragma unroll
    for (int nt=0;nt<4;++nt) acc[nt] = (f32x4){fc.x, fc.y, fc.z, fc.w};
  }
  float gacc[6] = {0.f,0.f,0.f,0.f,0.f,0.f};

  #pragma unroll 5
  for (int t=0;t<25;++t) {
    const int dy = t/5, dx = t%5;
    const int rowb = ((w+dy)*TW + dx)*80;
    // dense: 4 n-tiles of 16 px, one MFMA per tap each
    const uint4 aw = g_Wm[t*64 + l];
    const s16x8 af = __builtin_bit_cast(s16x8, aw);
    #pragma unroll
    for (int nt=0;nt<4;++nt) {
      const int off = rowb + (nt*16 + m)*80 + g*16;
      const s16x8 bf = __builtin_bit_cast(s16x8, *(const uint4*)(sb + off));
      acc[nt] = __builtin_amdgcn_mfma_f32_16x16x32_bf16(af, bf, acc[nt], 0, 0, 0);
    }
    // grouped k_vs2 (VALU), lane handles pixel l
    const int cg = rowb + l*80;
    const uint4 selr = *(const uint4*)(sb + cg + 16);
    const uint4 uvr  = *(const uint4*)(sb + cg + 32);
    float selv[6] = { bflo(selr.x), bfhi(selr.x), bflo(selr.y),
                      bfhi(selr.y), bflo(selr.z), bfhi(selr.z) };
    float uvf[6]  = { bflo(uvr.x), bfhi(uvr.x), bflo(uvr.y),
                      bfhi(uvr.y), bflo(uvr.z), bfhi(uvr.z) };
    const float* w2 = g_W2 + t*48;
    #pragma unroll
    for (int rr=0;rr<6;++rr) {
      float s = 0.f;
      #pragma unroll
      for (int j=0;j<6;++j) s = fmaf(w2[rr*8+j], uvf[j], s);
      gacc[rr] = fmaf(selv[rr], s, gacc[rr]);
    }
  }

  // center values (bf16) for thermo + Coriolis
  float Tc[3], ucv[3], vcv[3];
  {
    const int cc = ((w+2)*TW + (l+2))*80;
    const uint4 cS = *(const uint4*)(sb + cc + 16);
    const uint4 cU = *(const uint4*)(sb + cc + 32);
    Tc[0]=bflo(cS.x); Tc[1]=bfhi(cS.x); Tc[2]=bflo(cS.y);
    ucv[0]=bflo(cU.x); vcv[0]=bfhi(cU.x);
    ucv[1]=bflo(cU.y); vcv[1]=bfhi(cU.y);
    ucv[2]=bflo(cU.z); vcv[2]=bfhi(cU.z);
  }
  __syncthreads();                              // tile dead; reuse for transpose

  // transpose D fragments -> per-lane all 16 outputs (per-wave region)
  float* sf = (float*)s_mem;
  const int trb = w * (64*CELLL);
  #pragma unroll
  for (int nt=0;nt<4;++nt)
    *(f32x4*)(sf + trb + (nt*16 + m)*CELLL + g*4) = acc[nt];
  float y[16];
  #pragma unroll
  for (int q=0;q<4;++q) {
    float4 v = *(const float4*)(sf + trb + l*CELLL + q*4);
    y[4*q+0]=v.x; y[4*q+1]=v.y; y[4*q+2]=v.z; y[4*q+3]=v.w;
  }

  // ----------------- physics + RK4 ------------------------------------------
  const int c = c0 + l;
  const float fcv = f_cor[r];
  const float dtf = (float)(*dtp);
  const float an  = (stage==2) ? dtf : 0.5f*dtf;
  const float c6  = dtf/6.0f;
  const float p0=p_lev[0], p1=p_lev[1], p2=p_lev[2];
  const float dp0=delta_p[0], dp1=delta_p[1], dp2=delta_p[2];
  const float r10 = 1.0f/(p1-p0), r20 = 1.0f/(p2-p0), r21 = 1.0f/(p2-p1);
  const float roc = RGASC/CPC;
  const float rp0 = 1.0f/p0, rp1 = 1.0f/p1, rp2 = 1.0f/p2;
  const int OUT_T = BQ*3*HWQ*2;
  const int OUT_Q = OUT_T + BQ*3*HWQ;

  float dv[3], kT[3], kq[3], ku[3], kv[3];
  #pragma unroll
  for (int k=0;k<3;++k) {
    dv[k] = y[k];
    kT[k] = y[3+k] + gacc[k];
    kq[k] = y[6+k] + gacc[3+k];
    ku[k] = y[9+2*k]  + fcv*vcv[k];             // Coriolis (svp collapses to this)
    kv[k] = y[10+2*k] - fcv*ucv[k];
  }
  const float oh1 = dv[0]*dp0;
  const float oh2 = oh1 + dv[1]*dp1;
  const float oh3 = oh2 + dv[2]*dp2;
  const float om0 = 0.5f*oh1, om1 = 0.5f*(oh1+oh2), om2 = 0.5f*(oh2+oh3);
  kT[0] += om0*(roc*Tc[0]*rp0 - (Tc[1]-Tc[0])*r10);
  kT[1] += om1*(roc*Tc[1]*rp1 - (Tc[2]-Tc[0])*r20);
  kT[2] += om2*(roc*Tc[2]*rp2 - (Tc[2]-Tc[1])*r21);

  float Tn[3];
  #pragma unroll
  for (int k=0;k<3;++k) {
    const int pT = ((b*3+k)*HH + r)*WW + c;
    const int pU = pT*2;
    if (stage == 0) {
      g_aT[pT] = kT[k];  g_aq[pT] = kq[k];
      g_auv[pU] = ku[k]; g_auv[pU+1] = kv[k];
      Tn[k]      = T0[pT] + an*kT[k];
      g_Ts[pT]   = Tn[k];
      g_qs[pT]   = q0[pT] + an*kq[k];
      g_uvs[pU]   = uv0[pU]   + an*ku[k];
      g_uvs[pU+1] = uv0[pU+1] + an*kv[k];
    } else if (stage < 3) {
      g_aT[pT] += 2.0f*kT[k];  g_aq[pT] += 2.0f*kq[k];
      g_auv[pU] += 2.0f*ku[k]; g_auv[pU+1] += 2.0f*kv[k];
      Tn[k]      = T0[pT] + an*kT[k];
      g_Ts[pT]   = Tn[k];
      g_qs[pT]   = q0[pT] + an*kq[k];
      g_uvs[pU]   = uv0[pU]   + an*ku[k];
      g_uvs[pU+1] = uv0[pU+1] + an*kv[k];
    } else {
      out[pU]         = uv0[pU]   + c6*(g_auv[pU]   + ku[k]);
      out[pU+1]       = uv0[pU+1] + c6*(g_auv[pU+1] + kv[k]);
      out[OUT_T + pT] = T0[pT]    + c6*(g_aT[pT] + kT[k]);
      out[OUT_Q + pT] = q0[pT]    + c6*(g_aq[pT] + kq[k]);
    }
  }

  // partial sums of next-stage T for the mean (deterministic, no atomics)
  if (stage < 3) {
    #pragma unroll
    for (int k=0;k<3;++k) {
      float v = Tn[k];
      #pragma unroll
      for (int off=32; off; off >>= 1) v += __shfl_down(v, off);
      if (l == 0) s_red[w][k] = v;
    }
    __syncthreads();
    if (tid == 0) {
      #pragma unroll
      for (int k=0;k<3;++k)
        g_part[(b*3+k)*512 + blockIdx.y*8 + blockIdx.x] =
            s_red[0][k] + s_red[1][k] + s_red[2][k] + s_red[3][k];
    }
  }
}

// -----------------------------------------------------------------------------
extern "C" void kernel_launch(void* const* d_in, const int* in_sizes, int n_in,
                              void* d_out, int out_size, void* d_ws, size_t ws_size,
                              hipStream_t stream) {
  (void)in_sizes; (void)n_in; (void)d_ws; (void)ws_size; (void)out_size;
  const float* uv0   = (const float*)d_in[0];
  const float* T0    = (const float*)d_in[1];
  const float* q0    = (const float*)d_in[2];
  const float* k_ss  = (const float*)d_in[3];
  const float* k_vs  = (const float*)d_in[4];
  const float* k_sv  = (const float*)d_in[5];
  const float* k_vv  = (const float*)d_in[6];
  const float* k_vs2 = (const float*)d_in[7];
  const float* svp   = (const float*)d_in[9];  (void)svp;   // collapses to Coriolis
  const float* ke_w  = (const float*)d_in[10];
  const float* f_cor = (const float*)d_in[11];
  const float* p_lev = (const float*)d_in[12];
  const float* dpv   = (const float*)d_in[13];
  const int*   dtp   = (const int*)d_in[14];
  float* out = (float*)d_out;

  pack_kernel<<<27, 256, 0, stream>>>(k_ss, k_vs, k_sv, k_vv, k_vs2, f_cor);
  meanpart0_kernel<<<dim3(512,6), 256, 0, stream>>>(T0);
  meancomb_kernel<<<6, 64, 0, stream>>>();

  for (int st = 0; st < 4; ++st) {
    prep_kernel<<<1040, 256, 0, stream>>>(uv0, T0, q0, ke_w, st > 0);
    conv_kernel<<<dim3(8,64,2), 256, 0, stream>>>(
        f_cor, p_lev, dpv, uv0, T0, q0, out, dtp, st);
    if (st < 3) meancomb_kernel<<<6, 64, 0, stream>>>();
  }
}

// Round 4
// 103.094 us; speedup vs baseline: 29.0883x; 2.2215x over previous
//
#include <hip/hip_runtime.h>

#define HH 256
#define WW 512
#define BQ 2
#define HWQ (HH*WW)
#define TW 68             // LDS tile cols (64 + 4 halo)
#define TH 12             // LDS tile rows (8 out + 4 halo)
#define CSTR 80           // LDS cell stride bytes (data 64B)
#define TRL 20            // transpose stride (dwords)

#define RGASC 287.0f
#define CPC   1004.0f

typedef float f32x4 __attribute__((ext_vector_type(4)));
typedef short s16x8 __attribute__((ext_vector_type(8)));

// ---------------- static device scratch -------------------------------------
static __device__ uint4 g_Wm[25*64];          // packed A-fragments [tap][lane]
static __device__ float g_FC[HH*16];          // f_cor conv row-term [r][o]
static __device__ float g_S [HH*3*16];        // mean-correction  [r][k][o]
static __device__ float g_mean[8];
static __device__ float g_part[6*512];        // per-block partial sums for means
static __device__ float g_uvs[BQ*3*HWQ*2];    // stage state
static __device__ float g_Ts [BQ*3*HWQ];
static __device__ float g_qs [BQ*3*HWQ];
static __device__ float g_auv[BQ*3*HWQ*2];    // RK4 accumulators
static __device__ float g_aT [BQ*3*HWQ];
static __device__ float g_aq [BQ*3*HWQ];

// Cell slot map (32 bf16): s0-11: [T0,q0,u0,v0, T1,q1,u1,v1, T2,q2,u2,v2]
// s12-14: KE0-2, s15: 0, s16-21: zT (T_k*u_k, T_k*v_k), s22-27: zq, s28-31: 0.
// Output rows o: 0-2 DIV_k, 3-5 TK_k, 6-8 QK_k, 9-14 (U0,V0,U1,V1,U2,V2), 15 pad.

__device__ __forceinline__ unsigned short f2bf(float f) {   // RNE f32->bf16
  unsigned int u = __builtin_bit_cast(unsigned int, f);
  u += 0x7fffu + ((u >> 16) & 1u);
  return (unsigned short)(u >> 16);
}
__device__ __forceinline__ float bflo(unsigned int d) {
  return __builtin_bit_cast(float, d << 16);
}
__device__ __forceinline__ float bfhi(unsigned int d) {
  return __builtin_bit_cast(float, d & 0xffff0000u);
}
__device__ __forceinline__ int foMap(int o) {   // full scalar-output channel
  return (o < 3) ? 6*o + 3 : (o < 6) ? 6*(o-3) + 4 : 6*(o-6) + 5;
}

// ---------------- weight packing (once per launch) ---------------------------
__global__ __launch_bounds__(256) void pack_kernel(
    const float* __restrict__ k_ss, const float* __restrict__ k_vs,
    const float* __restrict__ k_sv, const float* __restrict__ k_vv,
    const float* __restrict__ k_vs2, const float* __restrict__ f_cor)
{
  int tid = blockIdx.x*256 + threadIdx.x;
  if (tid < 1600) {                       // A-fragments g_Wm[t][lane]
    int l = tid & 63, t = tid >> 6;
    int o = l & 15, g = l >> 4;
    int dy = t/5, dx = t%5;
    unsigned short h[8];
    #pragma unroll
    for (int e=0;e<8;++e) {
      int s = 8*g + e; float val = 0.f;
      if (o < 15) {
        int fo = foMap(o), vo = o - 9;
        if (s < 12) {
          int k = s >> 2, c4 = s & 3;
          if (c4 >= 2) {                  // u_k / v_k
            int j = 2*k + (c4-2);
            val = (o<9) ? k_vs[((fo*6+j)*5+dy)*5+dx]
                        : k_vv[((vo*6+j)*5+dy)*5+dx];
          } else {                        // T_k (+fold T_anom) / q_k
            int ifull = 6*k + ((c4==0) ? 4 : 5);
            val = (o<9) ? k_ss[((fo*19+ifull)*5+dy)*5+dx]
                        : k_sv[((vo*19+ifull)*5+dy)*5+dx];
            if (c4 == 0) {
              int ia = 6*k + 0;           // T_anom channel folded into T
              val += (o<9) ? k_ss[((fo*19+ia)*5+dy)*5+dx]
                           : k_sv[((vo*19+ia)*5+dy)*5+dx];
            }
          }
        } else if (s < 15) {              // KE_k
          int ifull = 6*(s-12) + 1;
          val = (o<9) ? k_ss[((fo*19+ifull)*5+dy)*5+dx]
                      : k_sv[((vo*19+ifull)*5+dy)*5+dx];
        } else if (s >= 16 && s < 22) {   // zT_{k,c} -> only output TK_k
          int k = (s-16)>>1, c = (s-16)&1;
          if (o == 3+k) val = k_vs2[(((6*k+4)*6 + 2*k+c)*5+dy)*5+dx];
        } else if (s >= 22 && s < 28) {   // zq_{k,c} -> only output QK_k
          int k = (s-22)>>1, c = (s-22)&1;
          if (o == 6+k) val = k_vs2[(((6*k+5)*6 + 2*k+c)*5+dy)*5+dx];
        }
      }
      h[e] = f2bf(val);
    }
    uint4 wv;
    wv.x = h[0] | ((unsigned)h[1]<<16);  wv.y = h[2] | ((unsigned)h[3]<<16);
    wv.z = h[4] | ((unsigned)h[5]<<16);  wv.w = h[6] | ((unsigned)h[7]<<16);
    g_Wm[tid] = wv;
  } else if (tid < 1600 + HH*16) {        // g_FC[r][o]: f_cor channel conv term
    int e = tid - 1600;
    int o = e & 15, r = e >> 4;
    float val = 0.f;
    if (o < 15) {
      int fo = foMap(o), vo = o - 9;
      for (int t=0;t<25;++t) {
        int dy = t/5, dx = t%5;
        int ar = r + dy - 2;
        if (ar < 0 || ar >= HH) continue;
        float f = f_cor[ar];
        float wv = (o<9) ? k_ss[((fo*19+18)*5+dy)*5+dx]
                         : k_sv[((vo*19+18)*5+dy)*5+dx];
        val += wv * f;
      }
    }
    g_FC[e] = val;
  } else if (tid < 1600 + HH*16 + HH*3*16) {  // g_S[r][k][o] mean-correction
    int e = tid - 1600 - HH*16;
    int o = e & 15; int rk = e >> 4;
    int k = rk % 3, r = rk / 3;
    float val = 0.f;
    if (o < 15) {
      int fo = foMap(o), vo = o - 9;
      int ia = 6*k + 0;                   // T_anom channel weight sum over valid taps
      for (int t=0;t<25;++t) {
        int dy = t/5, dx = t%5;
        int ar = r + dy - 2;
        if (ar < 0 || ar >= HH) continue;
        val += (o<9) ? k_ss[((fo*19+ia)*5+dy)*5+dx]
                     : k_sv[((vo*19+ia)*5+dy)*5+dx];
      }
    }
    g_S[e] = val;
  }
}

// ---------------- per-(b,level) partial means of input T ---------------------
__global__ __launch_bounds__(256) void meanpart0_kernel(const float* __restrict__ T0)
{
  int bk = blockIdx.y, chunk = blockIdx.x;
  float v = T0[bk*HWQ + chunk*256 + threadIdx.x];
  int l = threadIdx.x & 63, w = threadIdx.x >> 6;
  #pragma unroll
  for (int off=32; off; off >>= 1) v += __shfl_down(v, off);
  __shared__ float sr[4];
  if (l == 0) sr[w] = v;
  __syncthreads();
  if (threadIdx.x == 0) g_part[bk*512 + chunk] = sr[0]+sr[1]+sr[2]+sr[3];
}

__global__ __launch_bounds__(64) void meancomb_kernel(int nchunk)
{
  int bk = blockIdx.x, l = threadIdx.x;
  float s = 0.f;
  for (int i = l; i < nchunk; i += 64) s += g_part[bk*512 + i];
  #pragma unroll
  for (int off=32; off; off >>= 1) s += __shfl_down(s, off);
  if (l == 0) g_mean[bk] = s * (1.0f/(float)HWQ);
}

// ---------------- fused stage: build field + MFMA conv + physics + RK4 -------
__global__ __launch_bounds__(512, 4) void conv_kernel(
    const float* __restrict__ ke_w,
    const float* __restrict__ f_cor, const float* __restrict__ p_lev,
    const float* __restrict__ delta_p,
    const float* __restrict__ uv0, const float* __restrict__ T0,
    const float* __restrict__ q0,
    float* __restrict__ out, const int* __restrict__ dtp, int stage)
{
  __shared__ __align__(16) char s_raw[TH*TW*CSTR];   // 65280 B; reused for transpose
  __shared__ float s_red[8][3];

  const int tid = threadIdx.x;
  const int w   = tid >> 6;                     // wave 0..7 -> output row
  const int l   = tid & 63;
  const int b   = blockIdx.z;
  const int c0  = blockIdx.x << 6;
  const int R0  = blockIdx.y << 3;
  const int r   = R0 + w;

  const int useg = (stage > 0);
  const float* Tsrc = useg ? g_Ts  : T0;
  const float* qsrc = useg ? g_qs  : q0;
  const float* usrc = useg ? g_uvs : uv0;

  // ---- fused prep: raw f32 state -> bf16 cells (halo rows zero) -------------
  const float kw00=ke_w[0], kw01=ke_w[1], kw02=ke_w[2];
  const float kw10=ke_w[3], kw11=ke_w[4], kw12=ke_w[5];
  const float kw20=ke_w[6], kw21=ke_w[7], kw22=ke_w[8];
  for (int e = tid; e < TH*TW; e += 512) {
    int lr = e / TW, lc = e - lr*TW;
    int row = R0 + lr - 2;
    int col = (c0 + lc - 2) & (WW-1);
    unsigned int pk[16];
    #pragma unroll
    for (int i=0;i<16;++i) pk[i] = 0;
    if (row >= 0 && row < HH) {
      float T[3], q[3], u[3], v[3];
      #pragma unroll
      for (int k=0;k<3;++k) {
        int pix = ((b*3+k)*HH + row)*WW + col;
        T[k] = Tsrc[pix]; q[k] = qsrc[pix];
        float2 uvv = *(const float2*)(usrc + 2*pix);
        u[k] = uvv.x; v[k] = uvv.y;
      }
      float u2[3];
      #pragma unroll
      for (int k=0;k<3;++k) u2[k] = u[k]*u[k] + v[k]*v[k];
      float ke0 = kw00*u2[0] + kw01*u2[1] + kw02*u2[2];
      float ke1 = kw10*u2[0] + kw11*u2[1] + kw12*u2[2];
      float ke2 = kw20*u2[0] + kw21*u2[1] + kw22*u2[2];
      unsigned short hs[28];
      #pragma unroll
      for (int k=0;k<3;++k) {
        hs[4*k+0] = f2bf(T[k]); hs[4*k+1] = f2bf(q[k]);
        hs[4*k+2] = f2bf(u[k]); hs[4*k+3] = f2bf(v[k]);
      }
      hs[12]=f2bf(ke0); hs[13]=f2bf(ke1); hs[14]=f2bf(ke2); hs[15]=0;
      #pragma unroll
      for (int k=0;k<3;++k) {
        hs[16+2*k] = f2bf(T[k]*u[k]); hs[17+2*k] = f2bf(T[k]*v[k]);
        hs[22+2*k] = f2bf(q[k]*u[k]); hs[23+2*k] = f2bf(q[k]*v[k]);
      }
      #pragma unroll
      for (int i=0;i<14;++i) pk[i] = hs[2*i] | ((unsigned)hs[2*i+1] << 16);
    }
    uint4* dst = (uint4*)(s_raw + e*CSTR);
    dst[0] = make_uint4(pk[0],pk[1],pk[2],pk[3]);
    dst[1] = make_uint4(pk[4],pk[5],pk[6],pk[7]);
    dst[2] = make_uint4(pk[8],pk[9],pk[10],pk[11]);
    dst[3] = make_uint4(pk[12],pk[13],pk[14],pk[15]);
  }
  __syncthreads();

  // ---- acc init: f_cor row term + mean correction ---------------------------
  const int g = l >> 4;
  const int m = l & 15;
  f32x4 acc[4];
  {
    float4 fc = *(const float4*)(g_FC + r*16 + g*4);
    f32x4 base = (f32x4){fc.x, fc.y, fc.z, fc.w};
    #pragma unroll
    for (int k=0;k<3;++k) {
      float mk = g_mean[b*3+k];
      float4 sk = *(const float4*)(g_S + (r*3+k)*16 + g*4);
      base.x -= mk*sk.x; base.y -= mk*sk.y; base.z -= mk*sk.z; base.w -= mk*sk.w;
    }
    #pragma unroll
    for (int nt=0;nt<4;++nt) acc[nt] = base;
  }

  // ---- 25-tap MFMA loop ------------------------------------------------------
  const char* sb = s_raw;
  #pragma unroll 5
  for (int t=0;t<25;++t) {
    const int dy = t/5, dx = t%5;
    const uint4 aw = g_Wm[t*64 + l];
    const s16x8 af = __builtin_bit_cast(s16x8, aw);
    const int base = (((w+dy)*TW) + dx + m)*CSTR + g*16;
    #pragma unroll
    for (int nt=0;nt<4;++nt) {
      const s16x8 bf = __builtin_bit_cast(s16x8,
          *(const uint4*)(sb + base + nt*(16*CSTR)));
      acc[nt] = __builtin_amdgcn_mfma_f32_16x16x32_bf16(af, bf, acc[nt], 0, 0, 0);
    }
  }

  // center values (bf16) for thermo + Coriolis
  float Tc[3], ucv[3], vcv[3];
  {
    const char* cc = sb + (((w+2)*TW) + (l+2))*CSTR;
    const uint4 c0v = *(const uint4*)cc;        // s0-7
    const uint2 c1v = *(const uint2*)(cc + 16); // s8-11
    Tc[0]=bflo(c0v.x); ucv[0]=bflo(c0v.y); vcv[0]=bfhi(c0v.y);
    Tc[1]=bflo(c0v.z); ucv[1]=bflo(c0v.w); vcv[1]=bfhi(c0v.w);
    Tc[2]=bflo(c1v.x); ucv[2]=bflo(c1v.y); vcv[2]=bfhi(c1v.y);
  }
  __syncthreads();                              // tile dead; reuse for transpose

  // transpose D fragments -> per-lane all 16 outputs (per-wave region)
  float* sf = (float*)s_raw;
  const int trb = w * (64*TRL);
  #pragma unroll
  for (int nt=0;nt<4;++nt)
    *(f32x4*)(sf + trb + (nt*16 + m)*TRL + g*4) = acc[nt];
  float y[16];
  #pragma unroll
  for (int q=0;q<4;++q) {
    float4 v = *(const float4*)(sf + trb + l*TRL + q*4);
    y[4*q+0]=v.x; y[4*q+1]=v.y; y[4*q+2]=v.z; y[4*q+3]=v.w;
  }

  // ----------------- physics + RK4 ------------------------------------------
  const int c = c0 + l;
  const float fcv = f_cor[r];
  const float dtf = (float)(*dtp);
  const float an  = (stage==2) ? dtf : 0.5f*dtf;
  const float c6  = dtf/6.0f;
  const float p0=p_lev[0], p1=p_lev[1], p2=p_lev[2];
  const float dp0=delta_p[0], dp1=delta_p[1], dp2=delta_p[2];
  const float r10 = 1.0f/(p1-p0), r20 = 1.0f/(p2-p0), r21 = 1.0f/(p2-p1);
  const float roc = RGASC/CPC;
  const float rp0 = 1.0f/p0, rp1 = 1.0f/p1, rp2 = 1.0f/p2;
  const int OUT_T = BQ*3*HWQ*2;
  const int OUT_Q = OUT_T + BQ*3*HWQ;

  float dv[3], kT[3], kq[3], ku[3], kv[3];
  #pragma unroll
  for (int k=0;k<3;++k) {
    dv[k] = y[k];
    kT[k] = y[3+k];
    kq[k] = y[6+k];
    ku[k] = y[9+2*k]  + fcv*vcv[k];             // Coriolis (svp collapses to this)
    kv[k] = y[10+2*k] - fcv*ucv[k];
  }
  const float oh1 = dv[0]*dp0;
  const float oh2 = oh1 + dv[1]*dp1;
  const float oh3 = oh2 + dv[2]*dp2;
  const float om0 = 0.5f*oh1, om1 = 0.5f*(oh1+oh2), om2 = 0.5f*(oh2+oh3);
  kT[0] += om0*(roc*Tc[0]*rp0 - (Tc[1]-Tc[0])*r10);
  kT[1] += om1*(roc*Tc[1]*rp1 - (Tc[2]-Tc[0])*r20);
  kT[2] += om2*(roc*Tc[2]*rp2 - (Tc[2]-Tc[1])*r21);

  float Tn[3];
  #pragma unroll
  for (int k=0;k<3;++k) {
    const int pT = ((b*3+k)*HH + r)*WW + c;
    const int pU = pT*2;
    if (stage == 0) {
      g_aT[pT] = kT[k];  g_aq[pT] = kq[k];
      g_auv[pU] = ku[k]; g_auv[pU+1] = kv[k];
      Tn[k]      = T0[pT] + an*kT[k];
      g_Ts[pT]   = Tn[k];
      g_qs[pT]   = q0[pT] + an*kq[k];
      g_uvs[pU]   = uv0[pU]   + an*ku[k];
      g_uvs[pU+1] = uv0[pU+1] + an*kv[k];
    } else if (stage < 3) {
      g_aT[pT] += 2.0f*kT[k];  g_aq[pT] += 2.0f*kq[k];
      g_auv[pU] += 2.0f*ku[k]; g_auv[pU+1] += 2.0f*kv[k];
      Tn[k]      = T0[pT] + an*kT[k];
      g_Ts[pT]   = Tn[k];
      g_qs[pT]   = q0[pT] + an*kq[k];
      g_uvs[pU]   = uv0[pU]   + an*ku[k];
      g_uvs[pU+1] = uv0[pU+1] + an*kv[k];
    } else {
      out[pU]         = uv0[pU]   + c6*(g_auv[pU]   + ku[k]);
      out[pU+1]       = uv0[pU+1] + c6*(g_auv[pU+1] + kv[k]);
      out[OUT_T + pT] = T0[pT]    + c6*(g_aT[pT] + kT[k]);
      out[OUT_Q + pT] = q0[pT]    + c6*(g_aq[pT] + kq[k]);
    }
  }

  // partial sums of next-stage T for the mean (deterministic, no atomics)
  if (stage < 3) {
    #pragma unroll
    for (int k=0;k<3;++k) {
      float v = Tn[k];
      #pragma unroll
      for (int off=32; off; off >>= 1) v += __shfl_down(v, off);
      if (l == 0) s_red[w][k] = v;
    }
    __syncthreads();
    if (tid == 0) {
      #pragma unroll
      for (int k=0;k<3;++k) {
        float s = 0.f;
        #pragma unroll
        for (int ww=0;ww<8;++ww) s += s_red[ww][k];
        g_part[(b*3+k)*512 + blockIdx.y*8 + blockIdx.x] = s;
      }
    }
  }
}

// -----------------------------------------------------------------------------
extern "C" void kernel_launch(void* const* d_in, const int* in_sizes, int n_in,
                              void* d_out, int out_size, void* d_ws, size_t ws_size,
                              hipStream_t stream) {
  (void)in_sizes; (void)n_in; (void)d_ws; (void)ws_size; (void)out_size;
  const float* uv0   = (const float*)d_in[0];
  const float* T0    = (const float*)d_in[1];
  const float* q0    = (const float*)d_in[2];
  const float* k_ss  = (const float*)d_in[3];
  const float* k_vs  = (const float*)d_in[4];
  const float* k_sv  = (const float*)d_in[5];
  const float* k_vv  = (const float*)d_in[6];
  const float* k_vs2 = (const float*)d_in[7];
  const float* ke_w  = (const float*)d_in[10];
  const float* f_cor = (const float*)d_in[11];
  const float* p_lev = (const float*)d_in[12];
  const float* dpv   = (const float*)d_in[13];
  const int*   dtp   = (const int*)d_in[14];
  float* out = (float*)d_out;

  // pack: 1600 (Wm) + 4096 (FC) + 12288 (S) = 17984 items
  pack_kernel<<<71, 256, 0, stream>>>(k_ss, k_vs, k_sv, k_vv, k_vs2, f_cor);
  meanpart0_kernel<<<dim3(512,6), 256, 0, stream>>>(T0);
  meancomb_kernel<<<6, 64, 0, stream>>>(512);

  for (int st = 0; st < 4; ++st) {
    conv_kernel<<<dim3(8,32,2), 512, 0, stream>>>(
        ke_w, f_cor, p_lev, dpv, uv0, T0, q0, out, dtp, st);
    if (st < 3) meancomb_kernel<<<6, 64, 0, stream>>>(256);
  }
}

// Round 5
// 90.751 us; speedup vs baseline: 33.0446x; 1.1360x over previous
//
#include <hip/hip_runtime.h>

#define HH 256
#define WW 512
#define BQ 2
#define HWQ (HH*WW)
#define TW 68             // LDS tile cols (64 + 4 halo)
#define TH 12             // LDS tile rows (8 out + 4 halo)
#define CSTR 64           // LDS cell stride bytes (dense: contiguous 1KB tap reads)
#define TRL 20            // transpose stride (dwords)

#define RGASC 287.0f
#define CPC   1004.0f

typedef float f32x4 __attribute__((ext_vector_type(4)));
typedef short s16x8 __attribute__((ext_vector_type(8)));

// ---------------- static device scratch -------------------------------------
static __device__ uint4 g_Wm[25*64];          // packed A-fragments [tap][lane]
static __device__ float g_FC[HH*16];          // f_cor conv row-term [r][o]
static __device__ float g_S [HH*3*16];        // mean-correction  [r][k][o]
static __device__ float g_part[2][6*512];     // per-block partial sums (parity dbuf)
static __device__ float g_uvs[BQ*3*HWQ*2];    // stage state
static __device__ float g_Ts [BQ*3*HWQ];
static __device__ float g_qs [BQ*3*HWQ];
static __device__ float g_auv[BQ*3*HWQ*2];    // RK4 accumulators
static __device__ float g_aT [BQ*3*HWQ];
static __device__ float g_aq [BQ*3*HWQ];

// Cell slot map (32 bf16): s0-11: [T0,q0,u0,v0, T1,q1,u1,v1, T2,q2,u2,v2]
// s12-14: KE0-2, s15: 0, s16-21: zT (T_k*u_k, T_k*v_k), s22-27: zq, s28-31: 0.
// Output rows o: 0-2 DIV_k, 3-5 TK_k, 6-8 QK_k, 9-14 (U0,V0,U1,V1,U2,V2), 15 pad.

__device__ __forceinline__ unsigned short f2bf(float f) {   // RNE f32->bf16
  unsigned int u = __builtin_bit_cast(unsigned int, f);
  u += 0x7fffu + ((u >> 16) & 1u);
  return (unsigned short)(u >> 16);
}
__device__ __forceinline__ float bflo(unsigned int d) {
  return __builtin_bit_cast(float, d << 16);
}
__device__ __forceinline__ float bfhi(unsigned int d) {
  return __builtin_bit_cast(float, d & 0xffff0000u);
}
__device__ __forceinline__ int foMap(int o) {   // full scalar-output channel
  return (o < 3) ? 6*o + 3 : (o < 6) ? 6*(o-3) + 4 : 6*(o-6) + 5;
}

// ---------------- prelude: input-T partial means + weight packing ------------
__global__ __launch_bounds__(256) void prelude_kernel(
    const float* __restrict__ T0,
    const float* __restrict__ k_ss, const float* __restrict__ k_vs,
    const float* __restrict__ k_sv, const float* __restrict__ k_vv,
    const float* __restrict__ k_vs2, const float* __restrict__ f_cor)
{
  if (blockIdx.x < 3072) {                // meanpart: bk = bx>>9, chunk = bx&511
    int bk = blockIdx.x >> 9, chunk = blockIdx.x & 511;
    float v = T0[bk*HWQ + chunk*256 + threadIdx.x];
    int l = threadIdx.x & 63, w = threadIdx.x >> 6;
    #pragma unroll
    for (int off=32; off; off >>= 1) v += __shfl_down(v, off);
    __shared__ float sr[4];
    if (l == 0) sr[w] = v;
    __syncthreads();
    if (threadIdx.x == 0) g_part[0][bk*512 + chunk] = sr[0]+sr[1]+sr[2]+sr[3];
    return;
  }
  int tid = (blockIdx.x - 3072)*256 + threadIdx.x;
  if (tid < 1600) {                       // A-fragments g_Wm[t][lane]
    int l = tid & 63, t = tid >> 6;
    int o = l & 15, g = l >> 4;
    int dy = t/5, dx = t%5;
    unsigned short h[8];
    #pragma unroll
    for (int e=0;e<8;++e) {
      int s = 8*g + e; float val = 0.f;
      if (o < 15) {
        int fo = foMap(o), vo = o - 9;
        if (s < 12) {
          int k = s >> 2, c4 = s & 3;
          if (c4 >= 2) {                  // u_k / v_k
            int j = 2*k + (c4-2);
            val = (o<9) ? k_vs[((fo*6+j)*5+dy)*5+dx]
                        : k_vv[((vo*6+j)*5+dy)*5+dx];
          } else {                        // T_k (+fold T_anom) / q_k
            int ifull = 6*k + ((c4==0) ? 4 : 5);
            val = (o<9) ? k_ss[((fo*19+ifull)*5+dy)*5+dx]
                        : k_sv[((vo*19+ifull)*5+dy)*5+dx];
            if (c4 == 0) {
              int ia = 6*k + 0;           // T_anom channel folded into T
              val += (o<9) ? k_ss[((fo*19+ia)*5+dy)*5+dx]
                           : k_sv[((vo*19+ia)*5+dy)*5+dx];
            }
          }
        } else if (s < 15) {              // KE_k
          int ifull = 6*(s-12) + 1;
          val = (o<9) ? k_ss[((fo*19+ifull)*5+dy)*5+dx]
                      : k_sv[((vo*19+ifull)*5+dy)*5+dx];
        } else if (s >= 16 && s < 22) {   // zT_{k,c} -> only output TK_k
          int k = (s-16)>>1, c = (s-16)&1;
          if (o == 3+k) val = k_vs2[(((6*k+4)*6 + 2*k+c)*5+dy)*5+dx];
        } else if (s >= 22 && s < 28) {   // zq_{k,c} -> only output QK_k
          int k = (s-22)>>1, c = (s-22)&1;
          if (o == 6+k) val = k_vs2[(((6*k+5)*6 + 2*k+c)*5+dy)*5+dx];
        }
      }
      h[e] = f2bf(val);
    }
    uint4 wv;
    wv.x = h[0] | ((unsigned)h[1]<<16);  wv.y = h[2] | ((unsigned)h[3]<<16);
    wv.z = h[4] | ((unsigned)h[5]<<16);  wv.w = h[6] | ((unsigned)h[7]<<16);
    g_Wm[tid] = wv;
  } else if (tid < 1600 + HH*16) {        // g_FC[r][o]: f_cor channel conv term
    int e = tid - 1600;
    int o = e & 15, r = e >> 4;
    float val = 0.f;
    if (o < 15) {
      int fo = foMap(o), vo = o - 9;
      for (int t=0;t<25;++t) {
        int dy = t/5, dx = t%5;
        int ar = r + dy - 2;
        if (ar < 0 || ar >= HH) continue;
        float f = f_cor[ar];
        float wv = (o<9) ? k_ss[((fo*19+18)*5+dy)*5+dx]
                         : k_sv[((vo*19+18)*5+dy)*5+dx];
        val += wv * f;
      }
    }
    g_FC[e] = val;
  } else if (tid < 1600 + HH*16 + HH*3*16) {  // g_S[r][k][o] mean-correction
    int e = tid - 1600 - HH*16;
    int o = e & 15; int rk = e >> 4;
    int k = rk % 3, r = rk / 3;
    float val = 0.f;
    if (o < 15) {
      int fo = foMap(o), vo = o - 9;
      int ia = 6*k + 0;                   // T_anom weight sum over valid taps
      for (int t=0;t<25;++t) {
        int dy = t/5, dx = t%5;
        int ar = r + dy - 2;
        if (ar < 0 || ar >= HH) continue;
        val += (o<9) ? k_ss[((fo*19+ia)*5+dy)*5+dx]
                     : k_sv[((vo*19+ia)*5+dy)*5+dx];
      }
    }
    g_S[e] = val;
  }
}

// ---------------- fused stage: mean + build field + MFMA conv + RK4 ----------
__global__ __launch_bounds__(512, 4) void conv_kernel(
    const float* __restrict__ ke_w,
    const float* __restrict__ f_cor, const float* __restrict__ p_lev,
    const float* __restrict__ delta_p,
    const float* __restrict__ uv0, const float* __restrict__ T0,
    const float* __restrict__ q0,
    float* __restrict__ out, const int* __restrict__ dtp, int stage)
{
  __shared__ __align__(16) char s_raw[TH*TW*CSTR];   // 52224 B; reused for transpose
  __shared__ float s_red[8][3];
  __shared__ float s_mean[3];

  const int tid = threadIdx.x;
  const int w   = tid >> 6;                     // wave 0..7 -> output row
  const int l   = tid & 63;
  const int b   = blockIdx.z;
  const int c0  = blockIdx.x << 6;
  const int R0  = blockIdx.y << 3;
  const int r   = R0 + w;

  // ---- inline mean: waves 0-2 reduce this stage's partials ------------------
  if (w < 3) {
    const float* gp = g_part[stage & 1] + (b*3 + w)*512;
    float s;
    if (stage == 0) {
      s = gp[l] + gp[l+64] + gp[l+128] + gp[l+192]
        + gp[l+256] + gp[l+320] + gp[l+384] + gp[l+448];
    } else {
      s = gp[l] + gp[l+64] + gp[l+128] + gp[l+192];
    }
    #pragma unroll
    for (int off=32; off; off >>= 1) s += __shfl_down(s, off);
    if (l == 0) s_mean[w] = s * (1.0f/(float)HWQ);
  }

  const int useg = (stage > 0);
  const float* Tsrc = useg ? g_Ts  : T0;
  const float* qsrc = useg ? g_qs  : q0;
  const float* usrc = useg ? g_uvs : uv0;

  // ---- fused prep: raw f32 state -> bf16 cells (halo rows zero) -------------
  const float kw00=ke_w[0], kw01=ke_w[1], kw02=ke_w[2];
  const float kw10=ke_w[3], kw11=ke_w[4], kw12=ke_w[5];
  const float kw20=ke_w[6], kw21=ke_w[7], kw22=ke_w[8];
  for (int e = tid; e < TH*TW; e += 512) {
    int lr = e / TW, lc = e - lr*TW;
    int row = R0 + lr - 2;
    int col = (c0 + lc - 2) & (WW-1);
    unsigned int pk[16];
    #pragma unroll
    for (int i=0;i<16;++i) pk[i] = 0;
    if (row >= 0 && row < HH) {
      float T[3], q[3], u[3], v[3];
      #pragma unroll
      for (int k=0;k<3;++k) {
        int pix = ((b*3+k)*HH + row)*WW + col;
        T[k] = Tsrc[pix]; q[k] = qsrc[pix];
        float2 uvv = *(const float2*)(usrc + 2*pix);
        u[k] = uvv.x; v[k] = uvv.y;
      }
      float u2[3];
      #pragma unroll
      for (int k=0;k<3;++k) u2[k] = u[k]*u[k] + v[k]*v[k];
      float ke0 = kw00*u2[0] + kw01*u2[1] + kw02*u2[2];
      float ke1 = kw10*u2[0] + kw11*u2[1] + kw12*u2[2];
      float ke2 = kw20*u2[0] + kw21*u2[1] + kw22*u2[2];
      unsigned short hs[28];
      #pragma unroll
      for (int k=0;k<3;++k) {
        hs[4*k+0] = f2bf(T[k]); hs[4*k+1] = f2bf(q[k]);
        hs[4*k+2] = f2bf(u[k]); hs[4*k+3] = f2bf(v[k]);
      }
      hs[12]=f2bf(ke0); hs[13]=f2bf(ke1); hs[14]=f2bf(ke2); hs[15]=0;
      #pragma unroll
      for (int k=0;k<3;++k) {
        hs[16+2*k] = f2bf(T[k]*u[k]); hs[17+2*k] = f2bf(T[k]*v[k]);
        hs[22+2*k] = f2bf(q[k]*u[k]); hs[23+2*k] = f2bf(q[k]*v[k]);
      }
      #pragma unroll
      for (int i=0;i<14;++i) pk[i] = hs[2*i] | ((unsigned)hs[2*i+1] << 16);
    }
    uint4* dst = (uint4*)(s_raw + e*CSTR);
    dst[0] = make_uint4(pk[0],pk[1],pk[2],pk[3]);
    dst[1] = make_uint4(pk[4],pk[5],pk[6],pk[7]);
    dst[2] = make_uint4(pk[8],pk[9],pk[10],pk[11]);
    dst[3] = make_uint4(pk[12],pk[13],pk[14],pk[15]);
  }
  __syncthreads();

  // ---- acc init: f_cor row term + mean correction ---------------------------
  const int g = l >> 4;
  const int m = l & 15;
  f32x4 acc[4];
  {
    float4 fc = *(const float4*)(g_FC + r*16 + g*4);
    f32x4 base = (f32x4){fc.x, fc.y, fc.z, fc.w};
    #pragma unroll
    for (int k=0;k<3;++k) {
      float mk = s_mean[k];
      float4 sk = *(const float4*)(g_S + (r*3+k)*16 + g*4);
      base.x -= mk*sk.x; base.y -= mk*sk.y; base.z -= mk*sk.z; base.w -= mk*sk.w;
    }
    #pragma unroll
    for (int nt=0;nt<4;++nt) acc[nt] = base;
  }

  // ---- 25-tap MFMA loop: contiguous 1KB conflict-free B reads ----------------
  const char* sb = s_raw;
  #pragma unroll 5
  for (int t=0;t<25;++t) {
    const int dy = t/5, dx = t%5;
    const uint4 aw = g_Wm[t*64 + l];
    const s16x8 af = __builtin_bit_cast(s16x8, aw);
    const int base = (((w+dy)*TW) + dx + m)*CSTR + g*16;
    #pragma unroll
    for (int nt=0;nt<4;++nt) {
      const s16x8 bf = __builtin_bit_cast(s16x8,
          *(const uint4*)(sb + base + nt*(16*CSTR)));
      acc[nt] = __builtin_amdgcn_mfma_f32_16x16x32_bf16(af, bf, acc[nt], 0, 0, 0);
    }
  }

  // center values (bf16) for thermo + Coriolis
  float Tc[3], ucv[3], vcv[3];
  {
    const char* cc = sb + (((w+2)*TW) + (l+2))*CSTR;
    const uint4 c0v = *(const uint4*)cc;        // s0-7
    const uint2 c1v = *(const uint2*)(cc + 16); // s8-11
    Tc[0]=bflo(c0v.x); ucv[0]=bflo(c0v.y); vcv[0]=bfhi(c0v.y);
    Tc[1]=bflo(c0v.z); ucv[1]=bflo(c0v.w); vcv[1]=bfhi(c0v.w);
    Tc[2]=bflo(c1v.x); ucv[2]=bflo(c1v.y); vcv[2]=bfhi(c1v.y);
  }
  __syncthreads();                              // tile dead; reuse for transpose

  // transpose D fragments -> per-lane all 16 outputs (per-wave region)
  float* sf = (float*)s_raw;
  const int trb = w * (64*TRL);
  #pragma unroll
  for (int nt=0;nt<4;++nt)
    *(f32x4*)(sf + trb + (nt*16 + m)*TRL + g*4) = acc[nt];
  float y[16];
  #pragma unroll
  for (int q=0;q<4;++q) {
    float4 v = *(const float4*)(sf + trb + l*TRL + q*4);
    y[4*q+0]=v.x; y[4*q+1]=v.y; y[4*q+2]=v.z; y[4*q+3]=v.w;
  }

  // ----------------- physics + RK4 ------------------------------------------
  const int c = c0 + l;
  const float fcv = f_cor[r];
  const float dtf = (float)(*dtp);
  const float an  = (stage==2) ? dtf : 0.5f*dtf;
  const float c6  = dtf/6.0f;
  const float p0=p_lev[0], p1=p_lev[1], p2=p_lev[2];
  const float dp0=delta_p[0], dp1=delta_p[1], dp2=delta_p[2];
  const float r10 = 1.0f/(p1-p0), r20 = 1.0f/(p2-p0), r21 = 1.0f/(p2-p1);
  const float roc = RGASC/CPC;
  const float rp0 = 1.0f/p0, rp1 = 1.0f/p1, rp2 = 1.0f/p2;
  const int OUT_T = BQ*3*HWQ*2;
  const int OUT_Q = OUT_T + BQ*3*HWQ;

  float dv[3], kT[3], kq[3], ku[3], kv[3];
  #pragma unroll
  for (int k=0;k<3;++k) {
    dv[k] = y[k];
    kT[k] = y[3+k];
    kq[k] = y[6+k];
    ku[k] = y[9+2*k]  + fcv*vcv[k];             // Coriolis (svp collapses to this)
    kv[k] = y[10+2*k] - fcv*ucv[k];
  }
  const float oh1 = dv[0]*dp0;
  const float oh2 = oh1 + dv[1]*dp1;
  const float oh3 = oh2 + dv[2]*dp2;
  const float om0 = 0.5f*oh1, om1 = 0.5f*(oh1+oh2), om2 = 0.5f*(oh2+oh3);
  kT[0] += om0*(roc*Tc[0]*rp0 - (Tc[1]-Tc[0])*r10);
  kT[1] += om1*(roc*Tc[1]*rp1 - (Tc[2]-Tc[0])*r20);
  kT[2] += om2*(roc*Tc[2]*rp2 - (Tc[2]-Tc[1])*r21);

  float Tn[3];
  #pragma unroll
  for (int k=0;k<3;++k) {
    const int pT = ((b*3+k)*HH + r)*WW + c;
    const int pU = pT*2;
    if (stage == 0) {
      g_aT[pT] = kT[k];  g_aq[pT] = kq[k];
      g_auv[pU] = ku[k]; g_auv[pU+1] = kv[k];
      Tn[k]      = T0[pT] + an*kT[k];
      g_Ts[pT]   = Tn[k];
      g_qs[pT]   = q0[pT] + an*kq[k];
      g_uvs[pU]   = uv0[pU]   + an*ku[k];
      g_uvs[pU+1] = uv0[pU+1] + an*kv[k];
    } else if (stage < 3) {
      g_aT[pT] += 2.0f*kT[k];  g_aq[pT] += 2.0f*kq[k];
      g_auv[pU] += 2.0f*ku[k]; g_auv[pU+1] += 2.0f*kv[k];
      Tn[k]      = T0[pT] + an*kT[k];
      g_Ts[pT]   = Tn[k];
      g_qs[pT]   = q0[pT] + an*kq[k];
      g_uvs[pU]   = uv0[pU]   + an*ku[k];
      g_uvs[pU+1] = uv0[pU+1] + an*kv[k];
    } else {
      out[pU]         = uv0[pU]   + c6*(g_auv[pU]   + ku[k]);
      out[pU+1]       = uv0[pU+1] + c6*(g_auv[pU+1] + kv[k]);
      out[OUT_T + pT] = T0[pT]    + c6*(g_aT[pT] + kT[k]);
      out[OUT_Q + pT] = q0[pT]    + c6*(g_aq[pT] + kq[k]);
    }
  }

  // partial sums of next-stage T for the mean (write opposite parity buffer)
  if (stage < 3) {
    #pragma unroll
    for (int k=0;k<3;++k) {
      float v = Tn[k];
      #pragma unroll
      for (int off=32; off; off >>= 1) v += __shfl_down(v, off);
      if (l == 0) s_red[w][k] = v;
    }
    __syncthreads();
    if (tid == 0) {
      #pragma unroll
      for (int k=0;k<3;++k) {
        float s = 0.f;
        #pragma unroll
        for (int ww=0;ww<8;++ww) s += s_red[ww][k];
        g_part[(stage & 1) ^ 1][(b*3+k)*512 + blockIdx.y*8 + blockIdx.x] = s;
      }
    }
  }
}

// -----------------------------------------------------------------------------
extern "C" void kernel_launch(void* const* d_in, const int* in_sizes, int n_in,
                              void* d_out, int out_size, void* d_ws, size_t ws_size,
                              hipStream_t stream) {
  (void)in_sizes; (void)n_in; (void)d_ws; (void)ws_size; (void)out_size;
  const float* uv0   = (const float*)d_in[0];
  const float* T0    = (const float*)d_in[1];
  const float* q0    = (const float*)d_in[2];
  const float* k_ss  = (const float*)d_in[3];
  const float* k_vs  = (const float*)d_in[4];
  const float* k_sv  = (const float*)d_in[5];
  const float* k_vv  = (const float*)d_in[6];
  const float* k_vs2 = (const float*)d_in[7];
  const float* ke_w  = (const float*)d_in[10];
  const float* f_cor = (const float*)d_in[11];
  const float* p_lev = (const float*)d_in[12];
  const float* dpv   = (const float*)d_in[13];
  const int*   dtp   = (const int*)d_in[14];
  float* out = (float*)d_out;

  // prelude: 3072 mean-partial blocks + 71 pack blocks (17984 pack items)
  prelude_kernel<<<3143, 256, 0, stream>>>(T0, k_ss, k_vs, k_sv, k_vv, k_vs2, f_cor);

  for (int st = 0; st < 4; ++st) {
    conv_kernel<<<dim3(8,32,2), 512, 0, stream>>>(
        ke_w, f_cor, p_lev, dpv, uv0, T0, q0, out, dtp, st);
  }
}